// Round 11
// baseline (107.434 us; speedup 1.0000x reference)
//
#include <hip/hip_runtime.h>
#include <hip/hip_bf16.h>

#define NB 2
#define C_IN 64
#define N_SP 32768
#define NHEADS 4
#define DH 32
#define HID 128
#define QK_SCALE 0.17677669529663687f  // 32^-0.5
#define GN_EPS_C 1e-5f
#define NGN 2097152.0f                  // 64*32768

using bf16x8 = __attribute__((ext_vector_type(8))) short;
using f32x4  = __attribute__((ext_vector_type(4))) float;
using u16x4  = __attribute__((ext_vector_type(4))) unsigned short;
using u16x8  = __attribute__((ext_vector_type(8))) unsigned short;

__device__ __forceinline__ unsigned short f2bf(float f) {
    union { float f; unsigned u; } c{f};
    unsigned r = c.u + 0x7FFFu + ((c.u >> 16) & 1u);   // RNE
    return (unsigned short)(r >> 16);
}
__device__ __forceinline__ float bf2f(unsigned short u) {
    union { unsigned u; float f; } c{ (unsigned)u << 16 };
    return c.f;
}

// wave's x fragments: lane holds x[kk*32+lg*8+j][n0+s*16+lc]  (32 positions)
__device__ __forceinline__ void load_xf(const float* __restrict__ xb, int n0,
        int lg, int lc, bf16x8 xf[2][2]) {
#pragma unroll
    for (int s = 0; s < 2; ++s) {
        int n = n0 + s * 16 + lc;
#pragma unroll
        for (int kk = 0; kk < 2; ++kk) {
            bf16x8 v;
#pragma unroll
            for (int j = 0; j < 8; ++j)
                v[j] = (short)f2bf(xb[(size_t)(kk * 32 + lg * 8 + j) * N_SP + n]);
            xf[s][kk] = v;
        }
    }
}

// ==== kAB: k/v + ctx partials; last-64 tickets reduce + build Weff ==========
__global__ __launch_bounds__(512, 1) void kAB(const float* __restrict__ x,
        const float* __restrict__ wqkv, float* __restrict__ ctx_part,
        float* __restrict__ ksum_part, const float* __restrict__ wout,
        unsigned short* __restrict__ weff, unsigned int* __restrict__ ctr) {
    __shared__ unsigned short wl[32 * 64 * 8];   // k/v weight frags, 32 KB
    __shared__ unsigned short kt[2][8192];       // [ch 32][pos 256] swizzled
    __shared__ unsigned short vt[2][8192];
    __shared__ float cred2[2][128];
    __shared__ float cred[128];
    __shared__ float ks2[4][32];
    __shared__ float ksl[4];
    __shared__ int tks;
    const int t = threadIdx.x, wv = t >> 6, l = t & 63, lg = l >> 4, lc = l & 15;
    const int blk = blockIdx.x;
    const int b = blk >> 7, nblk = blk & 127;
    const int n0 = nblk * 256 + wv * 32;

    // stage w rows 128..383 (k then v) into bf16 MFMA A-frag layout
#pragma unroll
    for (int i = 0; i < 4; ++i) {
        int idx = t + i * 512;          // 0..2047 = (frag 0..31, lane)
        int f = idx >> 6, lane = idx & 63;
        int row = (8 + (f >> 1)) * 16 + (lane & 15);
        int c0 = (f & 1) * 32 + (lane >> 4) * 8;
        const float* wp = wqkv + row * 64 + c0;
        u16x8 pk;
#pragma unroll
        for (int j = 0; j < 8; ++j) pk[j] = f2bf(wp[j]);
        *(u16x8*)(wl + (size_t)idx * 8) = pk;
    }

    bf16x8 xf[2][2];
    load_xf(x + (size_t)b * C_IN * N_SP, n0, lg, lc, xf);
    __syncthreads();

    const int di = (wv >> 1) & 1, ei = wv & 1;   // ctx quadrant (waves 0..3)
#pragma unroll
    for (int h = 0; h < NHEADS; ++h) {
        const int bs = h & 1;
        f32x4 ka[2][2] = {}, va[2][2] = {};   // [s][e]
#pragma unroll
        for (int e = 0; e < 2; ++e)
#pragma unroll
            for (int kk = 0; kk < 2; ++kk) {
                bf16x8 wk = *(const bf16x8*)(wl + ((size_t)((2 * h + e) * 2 + kk) * 64 + l) * 8);
                bf16x8 wf = *(const bf16x8*)(wl + ((size_t)(16 + (2 * h + e) * 2 + kk) * 64 + l) * 8);
#pragma unroll
                for (int s = 0; s < 2; ++s) {
                    ka[s][e] = __builtin_amdgcn_mfma_f32_16x16x32_bf16(xf[s][kk], wk, ka[s][e], 0, 0, 0);
                    va[s][e] = __builtin_amdgcn_mfma_f32_16x16x32_bf16(xf[s][kk], wf, va[s][e], 0, 0, 0);
                }
            }
#pragma unroll
        for (int s = 0; s < 2; ++s)
#pragma unroll
            for (int e = 0; e < 2; ++e) {
                u16x4 pk, pv;
#pragma unroll
                for (int r = 0; r < 4; ++r) {
                    pk[r] = f2bf(__expf(ka[s][e][r]));
                    pv[r] = f2bf(va[s][e][r]);
                }
                int ch = e * 16 + lc;
                int pos = wv * 32 + s * 16 + lg * 4;
                int ba = (ch * 512 + pos * 2) ^ ((ch & 7) << 4);
                *(u16x4*)((char*)kt[bs] + ba) = pk;
                *(u16x4*)((char*)vt[bs] + ba) = pv;
            }
        __syncthreads();
        if (wv < 4) {
            f32x4 ca = {};
            float ks = 0.f;
#pragma unroll
            for (int k0 = 0; k0 < 256; k0 += 32) {
                int ar = di * 16 + lc, br = ei * 16 + lc;
                bf16x8 af = *(const bf16x8*)((const char*)kt[bs] + ((ar * 512 + (k0 + lg * 8) * 2) ^ ((ar & 7) << 4)));
                bf16x8 bf = *(const bf16x8*)((const char*)vt[bs] + ((br * 512 + (k0 + lg * 8) * 2) ^ ((br & 7) << 4)));
                if (ei == 0) {
#pragma unroll
                    for (int j = 0; j < 8; ++j) ks += bf2f((unsigned short)af[j]);
                }
                ca = __builtin_amdgcn_mfma_f32_16x16x32_bf16(af, bf, ca, 0, 0, 0);
            }
            float* cp = ctx_part + ((size_t)(b * 4 + h) * 128 + nblk) * 1024;
#pragma unroll
            for (int r = 0; r < 4; ++r)
                cp[(di * 16 + lg * 4 + r) * 32 + ei * 16 + lc] = ca[r];
            if (ei == 0) {
                ks += __shfl_xor(ks, 16);
                ks += __shfl_xor(ks, 32);
                if (lg == 0)
                    ksum_part[((size_t)(b * 4 + h) * 128 + nblk) * 32 + di * 16 + lc] = ks;
            }
        }
    }
    // ---- arrival ticket ----
    __syncthreads();                    // all global writes drained (vmcnt 0)
    if (t == 0) {
        __threadfence();                // publish this block's partials
        tks = (int)atomicAdd(ctr, 1u);
    }
    __syncthreads();
    const int ticket = tks;
    if (ticket < 192) return;

    // ---- spinners: wait for all 256 blocks, then one kB slice each ----
    if (t == 0) {
        while (atomicAdd(ctr, 0u) < 256u) __builtin_amdgcn_s_sleep(8);
    }
    __syncthreads();
    __threadfence();                    // acquire other blocks' partials
    const int sl = ticket - 192;        // 0..63
    const int g = sl >> 3, ds = sl & 7;
    const int bb = g >> 2, h = g & 3;
    float a = 0.f;
    if (t < 256) {
        const int tt = t & 127, th = t >> 7;
        const float* cp = ctx_part + ((size_t)g * 128 + th * 64) * 1024 + ds * 128 + tt;
#pragma unroll 8
        for (int i = 0; i < 64; ++i) a += cp[(size_t)i * 1024];
    }
    if (t < 256) cred2[t >> 7][t & 127] = a;
    if (t < 128) {
        int dl = t >> 5, ic = t & 31;
        float s = 0.f;
        const float* kp = ksum_part + ((size_t)g * 128 + ic * 4) * 32 + ds * 4 + dl;
#pragma unroll
        for (int i = 0; i < 4; ++i) s += kp[i * 32];
        ks2[dl][ic] = s;
    }
    __syncthreads();
    if (t < 128) cred[t] = cred2[0][t] + cred2[1][t];
    if (t < 4) {
        float s = 0.f;
#pragma unroll
        for (int i = 0; i < 32; ++i) s += ks2[t][i];
        ksl[t] = s;
    }
    __syncthreads();
    if (t < 256) {
        const int o = t >> 2, dl = t & 3;
        const float* wrow = wout + o * HID + h * 32;
        const float* crow = cred + dl * 32;
        float acc = 0.f;
#pragma unroll
        for (int e = 0; e < 32; ++e) acc = fmaf(wrow[e], crow[e], acc);
        acc /= ksl[dl];
        weff[((size_t)bb * 64 + o) * 128 + h * 32 + ds * 4 + dl] = f2bf(acc);
    }
}

// ==== kCE: q/softmax/y + stats; last-128 tickets finalize stats + GN out ====
__global__ __launch_bounds__(512, 1) void kCE(const float* __restrict__ x,
        const float* __restrict__ wqkv, const unsigned short* __restrict__ weff,
        const float* __restrict__ bout, unsigned short* __restrict__ y_t,
        float* __restrict__ pstats, const float* __restrict__ gnw,
        const float* __restrict__ gnb, float* __restrict__ out,
        unsigned int* __restrict__ ctr) {
    __shared__ unsigned short wl[16 * 64 * 8];  // q weight frags, 16 KB
    __shared__ unsigned short qt[256 * 128];    // [pos 256][ch 128] swizzled (64 KB)
    __shared__ float red[16];
    __shared__ float ms[2];
    __shared__ float w2s[64], b2s[64];
    __shared__ int tks;
    const int t = threadIdx.x, wv = t >> 6, l = t & 63, lg = l >> 4, lc = l & 15;
    const int blk = blockIdx.x;
    const int b = blk >> 7, nblk = blk & 127;
    const int n0 = nblk * 256 + wv * 32;

    // stage w rows 0..127 (q) into bf16 MFMA A-frag layout
#pragma unroll
    for (int i = 0; i < 2; ++i) {
        int idx = t + i * 512;          // 0..1023 = (frag 0..15, lane)
        int f = idx >> 6, lane = idx & 63;
        int row = (f >> 1) * 16 + (lane & 15);
        int c0 = (f & 1) * 32 + (lane >> 4) * 8;
        const float* wp = wqkv + row * 64 + c0;
        u16x8 pk;
#pragma unroll
        for (int j = 0; j < 8; ++j) pk[j] = f2bf(wp[j]);
        *(u16x8*)(wl + (size_t)idx * 8) = pk;
    }

    bf16x8 xf[2][2];
    load_xf(x + (size_t)b * C_IN * N_SP, n0, lg, lc, xf);
    __syncthreads();

    // q heads (A = w, B = x): D col = pos(lc), rows = q-ch
#pragma unroll
    for (int h = 0; h < NHEADS; ++h) {
        f32x4 qa[2][2] = {};   // [mi][s]
#pragma unroll
        for (int mi = 0; mi < 2; ++mi)
#pragma unroll
            for (int kk = 0; kk < 2; ++kk) {
                bf16x8 aq = *(const bf16x8*)(wl + ((size_t)((h * 2 + mi) * 2 + kk) * 64 + l) * 8);
#pragma unroll
                for (int s = 0; s < 2; ++s)
                    qa[mi][s] = __builtin_amdgcn_mfma_f32_16x16x32_bf16(aq, xf[s][kk], qa[mi][s], 0, 0, 0);
            }
#pragma unroll
        for (int s = 0; s < 2; ++s) {
            float m = -1e30f;
#pragma unroll
            for (int mi = 0; mi < 2; ++mi)
#pragma unroll
                for (int r = 0; r < 4; ++r) m = fmaxf(m, qa[mi][s][r]);
            m = fmaxf(m, __shfl_xor(m, 16));
            m = fmaxf(m, __shfl_xor(m, 32));
            float sum = 0.f;
#pragma unroll
            for (int mi = 0; mi < 2; ++mi)
#pragma unroll
                for (int r = 0; r < 4; ++r) {
                    float e = __expf(qa[mi][s][r] - m);
                    qa[mi][s][r] = e; sum += e;
                }
            sum += __shfl_xor(sum, 16);
            sum += __shfl_xor(sum, 32);
            float inv = QK_SCALE / sum;
            int pos = wv * 32 + s * 16 + lc;
            int swz = (pos & 7) << 4;
#pragma unroll
            for (int mi = 0; mi < 2; ++mi) {
                u16x4 pk;
#pragma unroll
                for (int r = 0; r < 4; ++r) pk[r] = f2bf(qa[mi][s][r] * inv);
                int ch0 = h * 32 + mi * 16 + lg * 4;
                *(u16x4*)((char*)qt + ((pos * 256 + ch0 * 2) ^ swz)) = pk;
            }
        }
    }
    // no barrier needed: each wave reads only its own pos rows of qt

    // y = Weff·q̂ : A = Weff[out-ch][q-ch], B = qt[q-ch][pos]
    f32x4 acc[4][2] = {};   // [mt][s]
    const unsigned short* wb = weff + (size_t)b * 8192;
#pragma unroll
    for (int kk = 0; kk < 4; ++kk) {
        bf16x8 bq[2];
#pragma unroll
        for (int s = 0; s < 2; ++s) {
            int pos = wv * 32 + s * 16 + lc;
            bq[s] = *(const bf16x8*)((const char*)qt +
                ((pos * 256 + (kk * 32 + lg * 8) * 2) ^ ((pos & 7) << 4)));
        }
#pragma unroll
        for (int mt = 0; mt < 4; ++mt) {
            bf16x8 af = *(const bf16x8*)(wb + (size_t)(mt * 16 + lc) * 128 + kk * 32 + lg * 8);
#pragma unroll
            for (int s = 0; s < 2; ++s)
                acc[mt][s] = __builtin_amdgcn_mfma_f32_16x16x32_bf16(af, bq[s], acc[mt][s], 0, 0, 0);
        }
    }
    // bias + stats + y_t store ([n][o] bf16)
    float s1 = 0.f, s2 = 0.f;
#pragma unroll
    for (int mt = 0; mt < 4; ++mt) {
        float bo[4];
#pragma unroll
        for (int r = 0; r < 4; ++r) bo[r] = bout[mt * 16 + lg * 4 + r];
#pragma unroll
        for (int s = 0; s < 2; ++s) {
            u16x4 pk;
#pragma unroll
            for (int r = 0; r < 4; ++r) {
                float val = acc[mt][s][r] + bo[r];
                s1 += val;
                s2 = fmaf(val, val, s2);
                pk[r] = f2bf(val);
            }
            int n = n0 + s * 16 + lc;
            *(u16x4*)(y_t + ((size_t)b * N_SP + n) * 64 + mt * 16 + lg * 4) = pk;
        }
    }
#pragma unroll
    for (int off = 32; off > 0; off >>= 1) {
        s1 += __shfl_down(s1, off, 64);
        s2 += __shfl_down(s2, off, 64);
    }
    if (l == 0) { red[wv * 2] = s1; red[wv * 2 + 1] = s2; }
    __syncthreads();
    if (t == 0) {
        float S1 = 0.f, S2 = 0.f;
#pragma unroll
        for (int w = 0; w < 8; ++w) { S1 += red[w * 2]; S2 += red[w * 2 + 1]; }
        pstats[(b * 128 + nblk) * 2]     = S1;
        pstats[(b * 128 + nblk) * 2 + 1] = S2;
    }
    // ---- arrival ticket ----
    __syncthreads();                    // all global writes drained
    if (t == 0) {
        __threadfence();
        tks = (int)atomicAdd(ctr, 1u);
    }
    __syncthreads();
    const int ticket = tks;
    if (ticket < 128) return;

    // ---- spinners: wait for all, finalize stats, apply GN to 2 tiles ----
    if (t == 0) {
        while (atomicAdd(ctr, 0u) < 256u) __builtin_amdgcn_s_sleep(8);
    }
    __syncthreads();
    __threadfence();
    const int tile0 = (ticket - 128) * 2;         // 2 consecutive tiles, same batch
    const int bb2 = tile0 >> 7;
    float a1 = 0.f, a2 = 0.f;
    if (t < 128) {
        a1 = pstats[(bb2 * 128 + t) * 2];
        a2 = pstats[(bb2 * 128 + t) * 2 + 1];
    }
#pragma unroll
    for (int off = 32; off > 0; off >>= 1) {
        a1 += __shfl_down(a1, off, 64);
        a2 += __shfl_down(a2, off, 64);
    }
    if (t < 128 && l == 0) { red[(t >> 6) * 2] = a1; red[(t >> 6) * 2 + 1] = a2; }
    __syncthreads();
    if (t == 0) {
        float S1 = red[0] + red[2], S2 = red[1] + red[3];
        float mean = S1 / NGN;
        float var = S2 / NGN - mean * mean;
        ms[0] = mean; ms[1] = rsqrtf(var + GN_EPS_C);
    }
    __syncthreads();
    if (t < 64) {
        float w2 = gnw[t] * ms[1];
        w2s[t] = w2;
        b2s[t] = gnb[t] - ms[0] * w2;
    }
    __syncthreads();
#pragma unroll
    for (int ti = 0; ti < 2; ++ti) {
        const int TT = tile0 + ti;
        const int n = (TT & 127) * 256 + (t & 255);
        const int o0 = (t >> 8) * 32;
        const unsigned short* yp = y_t + ((size_t)bb2 * N_SP + n) * 64 + o0;
        float* ob = out + (size_t)bb2 * C_IN * N_SP + n;
#pragma unroll
        for (int q8 = 0; q8 < 4; ++q8) {
            u16x8 v = *(const u16x8*)(yp + q8 * 8);
#pragma unroll
            for (int j = 0; j < 8; ++j) {
                int o = o0 + q8 * 8 + j;
                ob[(size_t)o * N_SP] = fmaf(bf2f((unsigned short)v[j]), w2s[o], b2s[o]);
            }
        }
    }
}

extern "C" void kernel_launch(void* const* d_in, const int* in_sizes, int n_in,
                              void* d_out, int out_size, void* d_ws, size_t ws_size,
                              hipStream_t stream) {
    const float* x    = (const float*)d_in[0];
    const float* wqkv = (const float*)d_in[1];
    const float* wout = (const float*)d_in[2];
    const float* bout = (const float*)d_in[3];
    const float* gnw  = (const float*)d_in[4];
    const float* gnb  = (const float*)d_in[5];
    float* out = (float*)d_out;

    char* ws = (char*)d_ws;
    size_t off = 0;
    unsigned int* ctr = (unsigned int*)(ws + off); off += 64;               // 2 counters
    float* ctx_part  = (float*)(ws + off); off += (size_t)8 * 128 * 1024 * 4;   // 4 MB
    float* ksum_part = (float*)(ws + off); off += (size_t)8 * 128 * 32 * 4;     // 128 KB
    unsigned short* weff = (unsigned short*)(ws + off); off += 2 * 8192 * 2;    // 32 KB
    unsigned short* y_t  = (unsigned short*)(ws + off); off += (size_t)NB * N_SP * 64 * 2;  // 8.4 MB
    float* pstats = (float*)(ws + off); off += NB * 128 * 2 * 4;

    hipMemsetAsync(ctr, 0, 64, stream);
    kAB<<<dim3(256), dim3(512), 0, stream>>>(x, wqkv, ctx_part, ksum_part, wout, weff, ctr + 0);
    kCE<<<dim3(256), dim3(512), 0, stream>>>(x, wqkv, weff, bout, y_t, pstats, gnw, gnb, out, ctr + 8);
}

// Round 12
// 47.293 us; speedup vs baseline: 2.2716x; 2.2716x over previous
//
#include <hip/hip_runtime.h>
#include <hip/hip_bf16.h>

#define NB 2
#define C_IN 64
#define N_SP 32768
#define NHEADS 4
#define DH 32
#define HID 128
#define QK_SCALE 0.17677669529663687f  // 32^-0.5
#define GN_EPS_C 1e-5f
#define NGN 2097152.0f                  // 64*32768
#define NPB 256                         // 128-pos blocks per batch

using bf16x8 = __attribute__((ext_vector_type(8))) short;
using f32x4  = __attribute__((ext_vector_type(4))) float;
using u16x4  = __attribute__((ext_vector_type(4))) unsigned short;
using u16x8  = __attribute__((ext_vector_type(8))) unsigned short;

__device__ __forceinline__ unsigned short f2bf(float f) {
    union { float f; unsigned u; } c{f};
    unsigned r = c.u + 0x7FFFu + ((c.u >> 16) & 1u);   // RNE
    return (unsigned short)(r >> 16);
}
__device__ __forceinline__ float bf2f(unsigned short u) {
    union { unsigned u; float f; } c{ (unsigned)u << 16 };
    return c.f;
}

// wave's x fragments: lane holds x[kk*32+lg*8+j][n0+s*16+lc]  (32 positions)
__device__ __forceinline__ void load_xf(const float* __restrict__ xb, int n0,
        int lg, int lc, bf16x8 xf[2][2]) {
#pragma unroll
    for (int s = 0; s < 2; ++s) {
        int n = n0 + s * 16 + lc;
#pragma unroll
        for (int kk = 0; kk < 2; ++kk) {
            bf16x8 v;
#pragma unroll
            for (int j = 0; j < 8; ++j)
                v[j] = (short)f2bf(xb[(size_t)(kk * 32 + lg * 8 + j) * N_SP + n]);
            xf[s][kk] = v;
        }
    }
}

// ==== kA: k/v per 128-pos block (4 waves, 2 blocks/CU), ctx partials ========
__global__ __launch_bounds__(256) void kA(const float* __restrict__ x,
        const float* __restrict__ wqkv,
        float* __restrict__ ctx_part, float* __restrict__ ksum_part) {
    __shared__ unsigned short wl[32 * 64 * 8];   // k/v weight frags, 32 KB
    __shared__ unsigned short kt[2][4096];       // [ch 32][pos 128] swizzled, dbuf
    __shared__ unsigned short vt[2][4096];
    const int t = threadIdx.x, wv = t >> 6, l = t & 63, lg = l >> 4, lc = l & 15;
    const int blk = blockIdx.x;
    const int b = blk >> 8, nblk = blk & (NPB - 1);
    const int n0 = nblk * 128 + wv * 32;

    // stage w rows 128..383 (k then v) into bf16 MFMA A-frag layout
#pragma unroll
    for (int i = 0; i < 8; ++i) {
        int idx = t + i * 256;          // 0..2047 = (frag 0..31, lane)
        int f = idx >> 6, lane = idx & 63;
        int row = (8 + (f >> 1)) * 16 + (lane & 15);
        int c0 = (f & 1) * 32 + (lane >> 4) * 8;
        const float* wp = wqkv + row * 64 + c0;
        u16x8 pk;
#pragma unroll
        for (int j = 0; j < 8; ++j) pk[j] = f2bf(wp[j]);
        *(u16x8*)(wl + (size_t)idx * 8) = pk;
    }

    bf16x8 xf[2][2];
    load_xf(x + (size_t)b * C_IN * N_SP, n0, lg, lc, xf);
    __syncthreads();

    const int di = (wv >> 1) & 1, ei = wv & 1;   // ctx quadrant
#pragma unroll
    for (int h = 0; h < NHEADS; ++h) {
        const int bs = h & 1;
        f32x4 ka[2][2] = {}, va[2][2] = {};   // [s][e]
#pragma unroll
        for (int e = 0; e < 2; ++e)
#pragma unroll
            for (int kk = 0; kk < 2; ++kk) {
                bf16x8 wk = *(const bf16x8*)(wl + ((size_t)((2 * h + e) * 2 + kk) * 64 + l) * 8);
                bf16x8 wf = *(const bf16x8*)(wl + ((size_t)(16 + (2 * h + e) * 2 + kk) * 64 + l) * 8);
#pragma unroll
                for (int s = 0; s < 2; ++s) {
                    ka[s][e] = __builtin_amdgcn_mfma_f32_16x16x32_bf16(xf[s][kk], wk, ka[s][e], 0, 0, 0);
                    va[s][e] = __builtin_amdgcn_mfma_f32_16x16x32_bf16(xf[s][kk], wf, va[s][e], 0, 0, 0);
                }
            }
        // D layout (A=x): row = pos-local (lg*4+r), col = ch-local (lc)
#pragma unroll
        for (int s = 0; s < 2; ++s)
#pragma unroll
            for (int e = 0; e < 2; ++e) {
                u16x4 pk, pv;
#pragma unroll
                for (int r = 0; r < 4; ++r) {
                    pk[r] = f2bf(__expf(ka[s][e][r]));
                    pv[r] = f2bf(va[s][e][r]);
                }
                int ch = e * 16 + lc;
                int pos = wv * 32 + s * 16 + lg * 4;
                int ba = (ch * 256 + pos * 2) ^ ((ch & 7) << 4);
                *(u16x4*)((char*)kt[bs] + ba) = pk;
                *(u16x4*)((char*)vt[bs] + ba) = pv;
            }
        __syncthreads();   // stores(h) visible; reads(h-2) fenced by barrier(h-1)
        // ctx tile (di, ei): contract over the block's 128 positions (all 4 waves)
        f32x4 ca = {};
        float ks = 0.f;
#pragma unroll
        for (int k0 = 0; k0 < 128; k0 += 32) {
            int ar = di * 16 + lc, br = ei * 16 + lc;
            bf16x8 af = *(const bf16x8*)((const char*)kt[bs] + ((ar * 256 + (k0 + lg * 8) * 2) ^ ((ar & 7) << 4)));
            bf16x8 bf = *(const bf16x8*)((const char*)vt[bs] + ((br * 256 + (k0 + lg * 8) * 2) ^ ((br & 7) << 4)));
            if (ei == 0) {
#pragma unroll
                for (int j = 0; j < 8; ++j) ks += bf2f((unsigned short)af[j]);
            }
            ca = __builtin_amdgcn_mfma_f32_16x16x32_bf16(af, bf, ca, 0, 0, 0);
        }
        float* cp = ctx_part + ((size_t)(b * 4 + h) * NPB + nblk) * 1024;
#pragma unroll
        for (int r = 0; r < 4; ++r)
            cp[(di * 16 + lg * 4 + r) * 32 + ei * 16 + lc] = ca[r];
        if (ei == 0) {
            ks += __shfl_xor(ks, 16);
            ks += __shfl_xor(ks, 32);
            if (lg == 0)
                ksum_part[((size_t)(b * 4 + h) * NPB + nblk) * 32 + di * 16 + lc] = ks;
        }
    }
}

// ==== kB: reduce ctx/ksum partials, Weff = wout·(ctx/ksum)  (64 blocks) =====
__global__ __launch_bounds__(256) void kB(const float* __restrict__ ctx_part,
        const float* __restrict__ ksum_part, const float* __restrict__ wout,
        unsigned short* __restrict__ weff) {
    __shared__ float cred2[2][128];
    __shared__ float cred[128];          // [4 d][32 e]
    __shared__ float ks2[4][32];
    __shared__ float ksl[4];
    const int blk = blockIdx.x;
    const int g = blk >> 3, ds = blk & 7;     // g = b*4+h; ds: 4-d slice
    const int bb = g >> 2, h = g & 3;
    const int t = threadIdx.x;
    const int tt = t & 127, th = t >> 7;
    float a = 0.f;
    const float* cp = ctx_part + ((size_t)g * NPB + th * 128) * 1024 + ds * 128 + tt;
#pragma unroll 8
    for (int i = 0; i < 128; ++i) a += cp[(size_t)i * 1024];
    cred2[th][tt] = a;
    if (t < 128) {
        int dl = t >> 5, ic = t & 31;
        float s = 0.f;
        const float* kp = ksum_part + ((size_t)g * NPB + ic * 8) * 32 + ds * 4 + dl;
#pragma unroll
        for (int i = 0; i < 8; ++i) s += kp[i * 32];
        ks2[dl][ic] = s;
    }
    __syncthreads();
    if (t < 128) cred[t] = cred2[0][t] + cred2[1][t];
    if (t < 4) {
        float s = 0.f;
#pragma unroll
        for (int i = 0; i < 32; ++i) s += ks2[t][i];
        ksl[t] = s;
    }
    __syncthreads();
    const int o = t >> 2, dl = t & 3;
    const float* wrow = wout + o * HID + h * 32;
    const float* crow = cred + dl * 32;
    float acc = 0.f;
#pragma unroll
    for (int e = 0; e < 32; ++e) acc = fmaf(wrow[e], crow[e], acc);
    acc /= ksl[dl];
    weff[((size_t)bb * 64 + o) * 128 + h * 32 + ds * 4 + dl] = f2bf(acc);
}

// ==== kC: q, softmax, y = Weff·q̂ (MFMA), stats, y_t bf16 (4 waves) ==========
__global__ __launch_bounds__(256) void kC(const float* __restrict__ x,
        const float* __restrict__ wqkv, const unsigned short* __restrict__ weff,
        const float* __restrict__ bout, unsigned short* __restrict__ y_t,
        float* __restrict__ pstats) {
    __shared__ unsigned short wl[16 * 64 * 8];  // q weight frags, 16 KB
    __shared__ unsigned short qt[128 * 128];    // [pos 128][ch 128] swizzled (32 KB)
    __shared__ float red[8];
    const int t = threadIdx.x, wv = t >> 6, l = t & 63, lg = l >> 4, lc = l & 15;
    const int blk = blockIdx.x;
    const int b = blk >> 8, nblk = blk & (NPB - 1);
    const int n0 = nblk * 128 + wv * 32;

    // stage w rows 0..127 (q) into bf16 MFMA A-frag layout
#pragma unroll
    for (int i = 0; i < 4; ++i) {
        int idx = t + i * 256;          // 0..1023 = (frag 0..15, lane)
        int f = idx >> 6, lane = idx & 63;
        int row = (f >> 1) * 16 + (lane & 15);
        int c0 = (f & 1) * 32 + (lane >> 4) * 8;
        const float* wp = wqkv + row * 64 + c0;
        u16x8 pk;
#pragma unroll
        for (int j = 0; j < 8; ++j) pk[j] = f2bf(wp[j]);
        *(u16x8*)(wl + (size_t)idx * 8) = pk;
    }

    bf16x8 xf[2][2];
    load_xf(x + (size_t)b * C_IN * N_SP, n0, lg, lc, xf);
    __syncthreads();

    // q heads (A = w, B = x): D col = pos(lc), rows = q-ch
#pragma unroll
    for (int h = 0; h < NHEADS; ++h) {
        f32x4 qa[2][2] = {};   // [mi][s]
#pragma unroll
        for (int mi = 0; mi < 2; ++mi)
#pragma unroll
            for (int kk = 0; kk < 2; ++kk) {
                bf16x8 aq = *(const bf16x8*)(wl + ((size_t)((h * 2 + mi) * 2 + kk) * 64 + l) * 8);
#pragma unroll
                for (int s = 0; s < 2; ++s)
                    qa[mi][s] = __builtin_amdgcn_mfma_f32_16x16x32_bf16(aq, xf[s][kk], qa[mi][s], 0, 0, 0);
            }
#pragma unroll
        for (int s = 0; s < 2; ++s) {
            float m = -1e30f;
#pragma unroll
            for (int mi = 0; mi < 2; ++mi)
#pragma unroll
                for (int r = 0; r < 4; ++r) m = fmaxf(m, qa[mi][s][r]);
            m = fmaxf(m, __shfl_xor(m, 16));
            m = fmaxf(m, __shfl_xor(m, 32));
            float sum = 0.f;
#pragma unroll
            for (int mi = 0; mi < 2; ++mi)
#pragma unroll
                for (int r = 0; r < 4; ++r) {
                    float e = __expf(qa[mi][s][r] - m);
                    qa[mi][s][r] = e; sum += e;
                }
            sum += __shfl_xor(sum, 16);
            sum += __shfl_xor(sum, 32);
            float inv = QK_SCALE / sum;
            int pos = wv * 32 + s * 16 + lc;
            int swz = (pos & 7) << 4;
#pragma unroll
            for (int mi = 0; mi < 2; ++mi) {
                u16x4 pk;
#pragma unroll
                for (int r = 0; r < 4; ++r) pk[r] = f2bf(qa[mi][s][r] * inv);
                int ch0 = h * 32 + mi * 16 + lg * 4;
                *(u16x4*)((char*)qt + ((pos * 256 + ch0 * 2) ^ swz)) = pk;
            }
        }
    }
    // no barrier needed: each wave reads only its own pos rows of qt

    // y = Weff·q̂ : A = Weff[out-ch][q-ch], B = qt[q-ch][pos]
    f32x4 acc[4][2] = {};   // [mt][s]
    const unsigned short* wb = weff + (size_t)b * 8192;
#pragma unroll
    for (int kk = 0; kk < 4; ++kk) {
        bf16x8 bq[2];
#pragma unroll
        for (int s = 0; s < 2; ++s) {
            int pos = wv * 32 + s * 16 + lc;
            bq[s] = *(const bf16x8*)((const char*)qt +
                ((pos * 256 + (kk * 32 + lg * 8) * 2) ^ ((pos & 7) << 4)));
        }
#pragma unroll
        for (int mt = 0; mt < 4; ++mt) {
            bf16x8 af = *(const bf16x8*)(wb + (size_t)(mt * 16 + lc) * 128 + kk * 32 + lg * 8);
#pragma unroll
            for (int s = 0; s < 2; ++s)
                acc[mt][s] = __builtin_amdgcn_mfma_f32_16x16x32_bf16(af, bq[s], acc[mt][s], 0, 0, 0);
        }
    }
    // bias + stats + y_t store ([n][o] bf16)
    float s1 = 0.f, s2 = 0.f;
#pragma unroll
    for (int mt = 0; mt < 4; ++mt) {
        float bo[4];
#pragma unroll
        for (int r = 0; r < 4; ++r) bo[r] = bout[mt * 16 + lg * 4 + r];
#pragma unroll
        for (int s = 0; s < 2; ++s) {
            u16x4 pk;
#pragma unroll
            for (int r = 0; r < 4; ++r) {
                float val = acc[mt][s][r] + bo[r];
                s1 += val;
                s2 = fmaf(val, val, s2);
                pk[r] = f2bf(val);
            }
            int n = n0 + s * 16 + lc;
            *(u16x4*)(y_t + ((size_t)b * N_SP + n) * 64 + mt * 16 + lg * 4) = pk;
        }
    }
#pragma unroll
    for (int off = 32; off > 0; off >>= 1) {
        s1 += __shfl_down(s1, off, 64);
        s2 += __shfl_down(s2, off, 64);
    }
    if (l == 0) { red[wv * 2] = s1; red[wv * 2 + 1] = s2; }
    __syncthreads();
    if (t == 0) {
        float S1 = red[0] + red[2] + red[4] + red[6];
        float S2 = red[1] + red[3] + red[5] + red[7];
        pstats[(b * NPB + nblk) * 2]     = S1;
        pstats[(b * NPB + nblk) * 2 + 1] = S2;
    }
}

// ==== kE: inline stats reduce (256 pairs), GN affine, y_t -> out ============
__global__ __launch_bounds__(256) void kE(const unsigned short* __restrict__ y_t,
        const float* __restrict__ pstats, const float* __restrict__ gnw,
        const float* __restrict__ gnb, float* __restrict__ out) {
    __shared__ float red[8];
    __shared__ float ms[2];
    __shared__ float w2s[64], b2s[64];
    const int t = threadIdx.x;
    const int blk = blockIdx.x;
    const int b = blk >> 9, nb = blk & 511;
    // reduce this batch's 256 stat pairs (redundant per block, L2-hot)
    float s1 = pstats[(b * NPB + t) * 2];
    float s2 = pstats[(b * NPB + t) * 2 + 1];
#pragma unroll
    for (int off = 32; off > 0; off >>= 1) {
        s1 += __shfl_down(s1, off, 64);
        s2 += __shfl_down(s2, off, 64);
    }
    if ((t & 63) == 0) { red[(t >> 6) * 2] = s1; red[(t >> 6) * 2 + 1] = s2; }
    __syncthreads();
    if (t == 0) {
        float S1 = red[0] + red[2] + red[4] + red[6];
        float S2 = red[1] + red[3] + red[5] + red[7];
        float mean = S1 / NGN;
        float var = S2 / NGN - mean * mean;
        ms[0] = mean; ms[1] = rsqrtf(var + GN_EPS_C);
    }
    __syncthreads();
    if (t < 64) {
        float w2 = gnw[t] * ms[1];
        w2s[t] = w2;
        b2s[t] = gnb[t] - ms[0] * w2;
    }
    __syncthreads();
    // n = nb*64 + (t&63): wave-contiguous out-writes (256 B per o-plane)
    const int n = nb * 64 + (t & 63), o0 = (t >> 6) * 16;
    const unsigned short* yp = y_t + ((size_t)b * N_SP + n) * 64 + o0;
    u16x8 v0 = *(const u16x8*)yp;
    u16x8 v1 = *(const u16x8*)(yp + 8);
    float* ob = out + (size_t)b * C_IN * N_SP + n;
#pragma unroll
    for (int j = 0; j < 8; ++j)
        ob[(size_t)(o0 + j) * N_SP] = fmaf(bf2f((unsigned short)v0[j]), w2s[o0 + j], b2s[o0 + j]);
#pragma unroll
    for (int j = 0; j < 8; ++j)
        ob[(size_t)(o0 + 8 + j) * N_SP] = fmaf(bf2f((unsigned short)v1[j]), w2s[o0 + 8 + j], b2s[o0 + 8 + j]);
}

extern "C" void kernel_launch(void* const* d_in, const int* in_sizes, int n_in,
                              void* d_out, int out_size, void* d_ws, size_t ws_size,
                              hipStream_t stream) {
    const float* x    = (const float*)d_in[0];
    const float* wqkv = (const float*)d_in[1];
    const float* wout = (const float*)d_in[2];
    const float* bout = (const float*)d_in[3];
    const float* gnw  = (const float*)d_in[4];
    const float* gnb  = (const float*)d_in[5];
    float* out = (float*)d_out;

    char* ws = (char*)d_ws;
    size_t off = 0;
    float* ctx_part  = (float*)(ws + off); off += (size_t)8 * NPB * 1024 * 4;   // 8 MB
    float* ksum_part = (float*)(ws + off); off += (size_t)8 * NPB * 32 * 4;     // 256 KB
    unsigned short* weff = (unsigned short*)(ws + off); off += 2 * 8192 * 2;    // 32 KB
    unsigned short* y_t  = (unsigned short*)(ws + off); off += (size_t)NB * N_SP * 64 * 2;  // 8.4 MB
    float* pstats = (float*)(ws + off); off += NB * NPB * 2 * 4;

    kA<<<dim3(NB * NPB), dim3(256), 0, stream>>>(x, wqkv, ctx_part, ksum_part);
    kB<<<dim3(64), dim3(256), 0, stream>>>(ctx_part, ksum_part, wout, weff);
    kC<<<dim3(NB * NPB), dim3(256), 0, stream>>>(x, wqkv, weff, bout, y_t, pstats);
    kE<<<dim3(1024), dim3(256), 0, stream>>>(y_t, pstats, gnw, gnb, out);
}

// Round 13
// 42.949 us; speedup vs baseline: 2.5014x; 1.1011x over previous
//
#include <hip/hip_runtime.h>
#include <hip/hip_bf16.h>

#define NB 2
#define C_IN 64
#define N_SP 32768
#define NHEADS 4
#define DH 32
#define HID 128
#define QK_SCALE 0.17677669529663687f  // 32^-0.5
#define GN_EPS_C 1e-5f
#define NGN 2097152.0f                  // 64*32768

using bf16x8 = __attribute__((ext_vector_type(8))) short;
using f32x4  = __attribute__((ext_vector_type(4))) float;
using u16x4  = __attribute__((ext_vector_type(4))) unsigned short;
using u16x8  = __attribute__((ext_vector_type(8))) unsigned short;

__device__ __forceinline__ unsigned short f2bf(float f) {
    union { float f; unsigned u; } c{f};
    unsigned r = c.u + 0x7FFFu + ((c.u >> 16) & 1u);   // RNE
    return (unsigned short)(r >> 16);
}
__device__ __forceinline__ float bf2f(unsigned short u) {
    union { unsigned u; float f; } c{ (unsigned)u << 16 };
    return c.f;
}

// wave's x fragments: lane holds x[kk*32+lg*8+j][n0+s*16+lc]  (32 positions)
__device__ __forceinline__ void load_xf(const float* __restrict__ xb, int n0,
        int lg, int lc, bf16x8 xf[2][2]) {
#pragma unroll
    for (int s = 0; s < 2; ++s) {
        int n = n0 + s * 16 + lc;
#pragma unroll
        for (int kk = 0; kk < 2; ++kk) {
            bf16x8 v;
#pragma unroll
            for (int j = 0; j < 8; ++j)
                v[j] = (short)f2bf(xb[(size_t)(kk * 32 + lg * 8 + j) * N_SP + n]);
            xf[s][kk] = v;
        }
    }
}

// ==== kA: qkv per 256-pos block; q̂ -> global frag blobs; k/v -> ctx ========
__global__ __launch_bounds__(512) void kA(const float* __restrict__ x,
        const float* __restrict__ wqkv, unsigned short* __restrict__ qs_frag,
        float* __restrict__ ctx_part, float* __restrict__ ksum_part) {
    __shared__ unsigned short wl[3072 * 8];      // all w frags (q,k,v), 48 KB
    __shared__ unsigned short kt[2][8192];       // [ch 32][pos 256] swizzled, dbuf
    __shared__ unsigned short vt[2][8192];
    const int t = threadIdx.x, wv = t >> 6, l = t & 63, lg = l >> 4, lc = l & 15;
    const int blk = blockIdx.x;
    const int b = blk >> 7, nblk = blk & 127;
    const int n0 = nblk * 256 + wv * 32;

    // stage ALL w rows 0..383 into bf16 MFMA A-frag layout (frag f = mt*2+kk)
#pragma unroll
    for (int i = 0; i < 6; ++i) {
        int idx = t + i * 512;          // 0..3071 = (frag, lane)
        int f = idx >> 6, lane = idx & 63;
        int row = (f >> 1) * 16 + (lane & 15);
        int c0 = (f & 1) * 32 + (lane >> 4) * 8;
        const float* wp = wqkv + row * 64 + c0;
        u16x8 pk;
#pragma unroll
        for (int j = 0; j < 8; ++j) pk[j] = f2bf(wp[j]);
        *(u16x8*)(wl + (size_t)idx * 8) = pk;
    }

    bf16x8 xf[2][2];
    load_xf(x + (size_t)b * C_IN * N_SP, n0, lg, lc, xf);
    __syncthreads();

    // ---- q phase: softmax + global frag-blob writes (fire-and-forget) ----
#pragma unroll
    for (int h = 0; h < NHEADS; ++h) {
        f32x4 qa[2][2] = {};   // [mi][s]
#pragma unroll
        for (int mi = 0; mi < 2; ++mi)
#pragma unroll
            for (int kk = 0; kk < 2; ++kk) {
                bf16x8 aq = *(const bf16x8*)(wl + ((size_t)((h * 2 + mi) * 2 + kk) * 64 + l) * 8);
#pragma unroll
                for (int s = 0; s < 2; ++s)
                    qa[mi][s] = __builtin_amdgcn_mfma_f32_16x16x32_bf16(aq, xf[s][kk], qa[mi][s], 0, 0, 0);
            }
#pragma unroll
        for (int s = 0; s < 2; ++s) {
            float m = -1e30f;
#pragma unroll
            for (int mi = 0; mi < 2; ++mi)
#pragma unroll
                for (int r = 0; r < 4; ++r) m = fmaxf(m, qa[mi][s][r]);
            m = fmaxf(m, __shfl_xor(m, 16));
            m = fmaxf(m, __shfl_xor(m, 32));
            float sum = 0.f;
#pragma unroll
            for (int mi = 0; mi < 2; ++mi)
#pragma unroll
                for (int r = 0; r < 4; ++r) {
                    float e = __expf(qa[mi][s][r] - m);
                    qa[mi][s][r] = e; sum += e;
                }
            sum += __shfl_xor(sum, 16);
            sum += __shfl_xor(sum, 32);
            float inv = QK_SCALE / sum;
            // blob keyed by pos16 = n>>4 and kk=h; lane' chosen so kC's
            // b128 read (lane (lgR,lcR), elem j) sees q̂[h*32+lgR*8+j][..lcR]
            int pos16 = nblk * 16 + wv * 2 + s;
            unsigned short* blob = qs_frag + ((size_t)(b * 2048 + pos16) * 4 + h) * 512;
#pragma unroll
            for (int mi = 0; mi < 2; ++mi) {
                u16x4 pk;
#pragma unroll
                for (int r = 0; r < 4; ++r) pk[r] = f2bf(qa[mi][s][r] * inv);
                int lanep = (mi * 2 + (lg >> 1)) * 16 + lc;
                *(u16x4*)(blob + (size_t)lanep * 8 + (lg & 1) * 4) = pk;
            }
        }
    }

    // ---- k/v + ctx phase (identical to r10) ----
    const int di = (wv >> 1) & 1, ei = wv & 1;   // ctx quadrant (waves 0..3)
#pragma unroll
    for (int h = 0; h < NHEADS; ++h) {
        const int bs = h & 1;
        f32x4 ka[2][2] = {}, va[2][2] = {};   // [s][e]
#pragma unroll
        for (int e = 0; e < 2; ++e)
#pragma unroll
            for (int kk = 0; kk < 2; ++kk) {
                bf16x8 wk = *(const bf16x8*)(wl + ((size_t)((8 + 2 * h + e) * 2 + kk) * 64 + l) * 8);
                bf16x8 wf = *(const bf16x8*)(wl + ((size_t)((16 + 2 * h + e) * 2 + kk) * 64 + l) * 8);
#pragma unroll
                for (int s = 0; s < 2; ++s) {
                    ka[s][e] = __builtin_amdgcn_mfma_f32_16x16x32_bf16(xf[s][kk], wk, ka[s][e], 0, 0, 0);
                    va[s][e] = __builtin_amdgcn_mfma_f32_16x16x32_bf16(xf[s][kk], wf, va[s][e], 0, 0, 0);
                }
            }
#pragma unroll
        for (int s = 0; s < 2; ++s)
#pragma unroll
            for (int e = 0; e < 2; ++e) {
                u16x4 pk, pv;
#pragma unroll
                for (int r = 0; r < 4; ++r) {
                    pk[r] = f2bf(__expf(ka[s][e][r]));
                    pv[r] = f2bf(va[s][e][r]);
                }
                int ch = e * 16 + lc;
                int pos = wv * 32 + s * 16 + lg * 4;
                int ba = (ch * 512 + pos * 2) ^ ((ch & 7) << 4);
                *(u16x4*)((char*)kt[bs] + ba) = pk;
                *(u16x4*)((char*)vt[bs] + ba) = pv;
            }
        __syncthreads();
        if (wv < 4) {
            f32x4 ca = {};
            float ks = 0.f;
#pragma unroll
            for (int k0 = 0; k0 < 256; k0 += 32) {
                int ar = di * 16 + lc, br = ei * 16 + lc;
                bf16x8 af = *(const bf16x8*)((const char*)kt[bs] + ((ar * 512 + (k0 + lg * 8) * 2) ^ ((ar & 7) << 4)));
                bf16x8 bf = *(const bf16x8*)((const char*)vt[bs] + ((br * 512 + (k0 + lg * 8) * 2) ^ ((br & 7) << 4)));
                if (ei == 0) {
#pragma unroll
                    for (int j = 0; j < 8; ++j) ks += bf2f((unsigned short)af[j]);
                }
                ca = __builtin_amdgcn_mfma_f32_16x16x32_bf16(af, bf, ca, 0, 0, 0);
            }
            float* cp = ctx_part + ((size_t)(b * 4 + h) * 128 + nblk) * 1024;
#pragma unroll
            for (int r = 0; r < 4; ++r)
                cp[(di * 16 + lg * 4 + r) * 32 + ei * 16 + lc] = ca[r];
            if (ei == 0) {
                ks += __shfl_xor(ks, 16);
                ks += __shfl_xor(ks, 32);
                if (lg == 0)
                    ksum_part[((size_t)(b * 4 + h) * 128 + nblk) * 32 + di * 16 + lc] = ks;
            }
        }
    }
}

// ==== kB: reduce ctx/ksum partials, Weff = wout·(ctx/ksum)  (64 blocks) =====
__global__ __launch_bounds__(256) void kB(const float* __restrict__ ctx_part,
        const float* __restrict__ ksum_part, const float* __restrict__ wout,
        unsigned short* __restrict__ weff) {
    __shared__ float cred2[2][128];
    __shared__ float cred[128];          // [4 d][32 e]
    __shared__ float ks2[4][32];
    __shared__ float ksl[4];
    const int blk = blockIdx.x;
    const int g = blk >> 3, ds = blk & 7;     // g = b*4+h; ds: 4-d slice
    const int bb = g >> 2, h = g & 3;
    const int t = threadIdx.x;
    const int tt = t & 127, th = t >> 7;
    float a = 0.f;
    const float* cp = ctx_part + ((size_t)g * 128 + th * 64) * 1024 + ds * 128 + tt;
#pragma unroll 8
    for (int i = 0; i < 64; ++i) a += cp[(size_t)i * 1024];
    cred2[th][tt] = a;
    if (t < 128) {
        int dl = t >> 5, ic = t & 31;
        float s = 0.f;
        const float* kp = ksum_part + ((size_t)g * 128 + ic * 4) * 32 + ds * 4 + dl;
#pragma unroll
        for (int i = 0; i < 4; ++i) s += kp[i * 32];
        ks2[dl][ic] = s;
    }
    __syncthreads();
    if (t < 128) cred[t] = cred2[0][t] + cred2[1][t];
    if (t < 4) {
        float s = 0.f;
#pragma unroll
        for (int i = 0; i < 32; ++i) s += ks2[t][i];
        ksl[t] = s;
    }
    __syncthreads();
    const int o = t >> 2, dl = t & 3;
    const float* wrow = wout + o * HID + h * 32;
    const float* crow = cred + dl * 32;
    float acc = 0.f;
#pragma unroll
    for (int e = 0; e < 32; ++e) acc = fmaf(wrow[e], crow[e], acc);
    acc /= ksl[dl];
    weff[((size_t)bb * 64 + o) * 128 + h * 32 + ds * 4 + dl] = f2bf(acc);
}

// ==== kC: y = Weff·q̂ from global frags; stats; y_t (pure PV, no LDS) =======
__global__ __launch_bounds__(256) void kC(const unsigned short* __restrict__ qs_frag,
        const unsigned short* __restrict__ weff, const float* __restrict__ bout,
        unsigned short* __restrict__ y_t, float* __restrict__ pstats) {
    __shared__ float red[8];
    const int t = threadIdx.x, wv = t >> 6, l = t & 63, lg = l >> 4, lc = l & 15;
    const int blk = blockIdx.x;
    const int b = blk >> 8, nblk = blk & 255;
    const int n0 = nblk * 128 + wv * 32;

    f32x4 acc[4][2] = {};   // [mt][s]
    const unsigned short* wb = weff + (size_t)b * 8192;
#pragma unroll
    for (int kk = 0; kk < 4; ++kk) {
        bf16x8 bq[2];
#pragma unroll
        for (int s = 0; s < 2; ++s) {
            int pos16 = nblk * 8 + wv * 2 + s;
            bq[s] = *(const bf16x8*)(qs_frag +
                ((size_t)(b * 2048 + pos16) * 4 + kk) * 512 + (size_t)l * 8);
        }
#pragma unroll
        for (int mt = 0; mt < 4; ++mt) {
            bf16x8 af = *(const bf16x8*)(wb + (size_t)(mt * 16 + lc) * 128 + kk * 32 + lg * 8);
#pragma unroll
            for (int s = 0; s < 2; ++s)
                acc[mt][s] = __builtin_amdgcn_mfma_f32_16x16x32_bf16(af, bq[s], acc[mt][s], 0, 0, 0);
        }
    }
    // bias + stats + y_t store ([n][o] bf16)
    float s1 = 0.f, s2 = 0.f;
#pragma unroll
    for (int mt = 0; mt < 4; ++mt) {
        float bo[4];
#pragma unroll
        for (int r = 0; r < 4; ++r) bo[r] = bout[mt * 16 + lg * 4 + r];
#pragma unroll
        for (int s = 0; s < 2; ++s) {
            u16x4 pk;
#pragma unroll
            for (int r = 0; r < 4; ++r) {
                float val = acc[mt][s][r] + bo[r];
                s1 += val;
                s2 = fmaf(val, val, s2);
                pk[r] = f2bf(val);
            }
            int n = n0 + s * 16 + lc;
            *(u16x4*)(y_t + ((size_t)b * N_SP + n) * 64 + mt * 16 + lg * 4) = pk;
        }
    }
#pragma unroll
    for (int off = 32; off > 0; off >>= 1) {
        s1 += __shfl_down(s1, off, 64);
        s2 += __shfl_down(s2, off, 64);
    }
    if (l == 0) { red[wv * 2] = s1; red[wv * 2 + 1] = s2; }
    __syncthreads();
    if (t == 0) {
        float S1 = red[0] + red[2] + red[4] + red[6];
        float S2 = red[1] + red[3] + red[5] + red[7];
        pstats[(b * 256 + nblk) * 2]     = S1;
        pstats[(b * 256 + nblk) * 2 + 1] = S2;
    }
}

// ==== kE: inline stats reduce (256 pairs), GN affine, y_t -> out ============
__global__ __launch_bounds__(256) void kE(const unsigned short* __restrict__ y_t,
        const float* __restrict__ pstats, const float* __restrict__ gnw,
        const float* __restrict__ gnb, float* __restrict__ out) {
    __shared__ float red[8];
    __shared__ float ms[2];
    __shared__ float w2s[64], b2s[64];
    const int t = threadIdx.x;
    const int blk = blockIdx.x;
    const int b = blk >> 9, nb = blk & 511;
    // reduce this batch's 256 stat pairs (redundant per block, L2-hot)
    float s1 = pstats[(b * 256 + t) * 2];
    float s2 = pstats[(b * 256 + t) * 2 + 1];
#pragma unroll
    for (int off = 32; off > 0; off >>= 1) {
        s1 += __shfl_down(s1, off, 64);
        s2 += __shfl_down(s2, off, 64);
    }
    if ((t & 63) == 0) { red[(t >> 6) * 2] = s1; red[(t >> 6) * 2 + 1] = s2; }
    __syncthreads();
    if (t == 0) {
        float S1 = red[0] + red[2] + red[4] + red[6];
        float S2 = red[1] + red[3] + red[5] + red[7];
        float mean = S1 / NGN;
        float var = S2 / NGN - mean * mean;
        ms[0] = mean; ms[1] = rsqrtf(var + GN_EPS_C);
    }
    __syncthreads();
    if (t < 64) {
        float w2 = gnw[t] * ms[1];
        w2s[t] = w2;
        b2s[t] = gnb[t] - ms[0] * w2;
    }
    __syncthreads();
    // n = nb*64 + (t&63): wave-contiguous out-writes (256 B per o-plane)
    const int n = nb * 64 + (t & 63), o0 = (t >> 6) * 16;
    const unsigned short* yp = y_t + ((size_t)b * N_SP + n) * 64 + o0;
    u16x8 v0 = *(const u16x8*)yp;
    u16x8 v1 = *(const u16x8*)(yp + 8);
    float* ob = out + (size_t)b * C_IN * N_SP + n;
#pragma unroll
    for (int j = 0; j < 8; ++j)
        ob[(size_t)(o0 + j) * N_SP] = fmaf(bf2f((unsigned short)v0[j]), w2s[o0 + j], b2s[o0 + j]);
#pragma unroll
    for (int j = 0; j < 8; ++j)
        ob[(size_t)(o0 + 8 + j) * N_SP] = fmaf(bf2f((unsigned short)v1[j]), w2s[o0 + 8 + j], b2s[o0 + 8 + j]);
}

extern "C" void kernel_launch(void* const* d_in, const int* in_sizes, int n_in,
                              void* d_out, int out_size, void* d_ws, size_t ws_size,
                              hipStream_t stream) {
    const float* x    = (const float*)d_in[0];
    const float* wqkv = (const float*)d_in[1];
    const float* wout = (const float*)d_in[2];
    const float* bout = (const float*)d_in[3];
    const float* gnw  = (const float*)d_in[4];
    const float* gnb  = (const float*)d_in[5];
    float* out = (float*)d_out;

    char* ws = (char*)d_ws;
    size_t off = 0;
    unsigned short* qs_frag = (unsigned short*)(ws + off); off += (size_t)NB * 2048 * 4 * 512 * 2;  // 16.8 MB
    float* ctx_part  = (float*)(ws + off); off += (size_t)8 * 128 * 1024 * 4;   // 4 MB
    float* ksum_part = (float*)(ws + off); off += (size_t)8 * 128 * 32 * 4;     // 128 KB
    unsigned short* weff = (unsigned short*)(ws + off); off += 2 * 8192 * 2;    // 32 KB
    unsigned short* y_t  = (unsigned short*)(ws + off); off += (size_t)NB * N_SP * 64 * 2;  // 8.4 MB
    float* pstats = (float*)(ws + off); off += NB * 256 * 2 * 4;

    kA<<<dim3(256), dim3(512), 0, stream>>>(x, wqkv, qs_frag, ctx_part, ksum_part);
    kB<<<dim3(64), dim3(256), 0, stream>>>(ctx_part, ksum_part, wout, weff);
    kC<<<dim3(512), dim3(256), 0, stream>>>(qs_frag, weff, bout, y_t, pstats);
    kE<<<dim3(1024), dim3(256), 0, stream>>>(y_t, pstats, gnw, gnb, out);
}

// Round 14
// 41.199 us; speedup vs baseline: 2.6077x; 1.0425x over previous
//
#include <hip/hip_runtime.h>
#include <hip/hip_bf16.h>

#define NB 2
#define C_IN 64
#define N_SP 32768
#define NHEADS 4
#define DH 32
#define HID 128
#define QK_SCALE 0.17677669529663687f  // 32^-0.5
#define GN_EPS_C 1e-5f
#define NGN 2097152.0f                  // 64*32768

using bf16x8 = __attribute__((ext_vector_type(8))) short;
using f32x4  = __attribute__((ext_vector_type(4))) float;
using u16x4  = __attribute__((ext_vector_type(4))) unsigned short;
using u16x8  = __attribute__((ext_vector_type(8))) unsigned short;

__device__ __forceinline__ unsigned short f2bf(float f) {
    union { float f; unsigned u; } c{f};
    unsigned r = c.u + 0x7FFFu + ((c.u >> 16) & 1u);   // RNE
    return (unsigned short)(r >> 16);
}
__device__ __forceinline__ float bf2f(unsigned short u) {
    union { unsigned u; float f; } c{ (unsigned)u << 16 };
    return c.f;
}

// wave's x fragments: lane holds x[kk*32+lg*8+j][n0+s*16+lc]  (32 positions)
__device__ __forceinline__ void load_xf(const float* __restrict__ xb, int n0,
        int lg, int lc, bf16x8 xf[2][2]) {
#pragma unroll
    for (int s = 0; s < 2; ++s) {
        int n = n0 + s * 16 + lc;
#pragma unroll
        for (int kk = 0; kk < 2; ++kk) {
            bf16x8 v;
#pragma unroll
            for (int j = 0; j < 8; ++j)
                v[j] = (short)f2bf(xb[(size_t)(kk * 32 + lg * 8 + j) * N_SP + n]);
            xf[s][kk] = v;
        }
    }
}

// ==== kA: qkv per 256-pos block; q̂ -> global frag blobs; k/v -> ctx ========
__global__ __launch_bounds__(512) void kA(const float* __restrict__ x,
        const float* __restrict__ wqkv, unsigned short* __restrict__ qs_frag,
        float* __restrict__ ctx_part, float* __restrict__ ksum_part) {
    __shared__ unsigned short wl[3072 * 8];      // all w frags (q,k,v), 48 KB
    __shared__ unsigned short kt[2][8192];       // [ch 32][pos 256] swizzled, dbuf
    __shared__ unsigned short vt[2][8192];
    const int t = threadIdx.x, wv = t >> 6, l = t & 63, lg = l >> 4, lc = l & 15;
    const int blk = blockIdx.x;
    const int b = blk >> 7, nblk = blk & 127;
    const int n0 = nblk * 256 + wv * 32;

    // x loads FIRST: longest-latency (HBM) loads issue before the L2 w-stage
    bf16x8 xf[2][2];
    load_xf(x + (size_t)b * C_IN * N_SP, n0, lg, lc, xf);

    // stage ALL w rows 0..383 into bf16 MFMA A-frag layout (frag f = mt*2+kk)
#pragma unroll
    for (int i = 0; i < 6; ++i) {
        int idx = t + i * 512;          // 0..3071 = (frag, lane)
        int f = idx >> 6, lane = idx & 63;
        int row = (f >> 1) * 16 + (lane & 15);
        int c0 = (f & 1) * 32 + (lane >> 4) * 8;
        const float* wp = wqkv + row * 64 + c0;
        u16x8 pk;
#pragma unroll
        for (int j = 0; j < 8; ++j) pk[j] = f2bf(wp[j]);
        *(u16x8*)(wl + (size_t)idx * 8) = pk;
    }
    __syncthreads();

    // ---- q phase: softmax (no max-sub; |q|<~10 so exp is safe) ----
#pragma unroll
    for (int h = 0; h < NHEADS; ++h) {
        f32x4 qa[2][2] = {};   // [mi][s]
#pragma unroll
        for (int mi = 0; mi < 2; ++mi)
#pragma unroll
            for (int kk = 0; kk < 2; ++kk) {
                bf16x8 aq = *(const bf16x8*)(wl + ((size_t)((h * 2 + mi) * 2 + kk) * 64 + l) * 8);
#pragma unroll
                for (int s = 0; s < 2; ++s)
                    qa[mi][s] = __builtin_amdgcn_mfma_f32_16x16x32_bf16(aq, xf[s][kk], qa[mi][s], 0, 0, 0);
            }
#pragma unroll
        for (int s = 0; s < 2; ++s) {
            float sum = 0.f;
#pragma unroll
            for (int mi = 0; mi < 2; ++mi)
#pragma unroll
                for (int r = 0; r < 4; ++r) {
                    float e = __expf(qa[mi][s][r]);
                    qa[mi][s][r] = e; sum += e;
                }
            sum += __shfl_xor(sum, 16);
            sum += __shfl_xor(sum, 32);
            float inv = QK_SCALE / sum;
            int pos16 = nblk * 16 + wv * 2 + s;
            unsigned short* blob = qs_frag + ((size_t)(b * 2048 + pos16) * 4 + h) * 512;
#pragma unroll
            for (int mi = 0; mi < 2; ++mi) {
                u16x4 pk;
#pragma unroll
                for (int r = 0; r < 4; ++r) pk[r] = f2bf(qa[mi][s][r] * inv);
                int lanep = (mi * 2 + (lg >> 1)) * 16 + lc;
                *(u16x4*)(blob + (size_t)lanep * 8 + (lg & 1) * 4) = pk;
            }
        }
    }

    // ---- k/v + ctx phase ----
    const int di = (wv >> 1) & 1, ei = wv & 1;   // ctx quadrant (waves 0..3)
#pragma unroll
    for (int h = 0; h < NHEADS; ++h) {
        const int bs = h & 1;
        f32x4 ka[2][2] = {}, va[2][2] = {};   // [s][e]
#pragma unroll
        for (int e = 0; e < 2; ++e)
#pragma unroll
            for (int kk = 0; kk < 2; ++kk) {
                bf16x8 wk = *(const bf16x8*)(wl + ((size_t)((8 + 2 * h + e) * 2 + kk) * 64 + l) * 8);
                bf16x8 wf = *(const bf16x8*)(wl + ((size_t)((16 + 2 * h + e) * 2 + kk) * 64 + l) * 8);
#pragma unroll
                for (int s = 0; s < 2; ++s) {
                    ka[s][e] = __builtin_amdgcn_mfma_f32_16x16x32_bf16(xf[s][kk], wk, ka[s][e], 0, 0, 0);
                    va[s][e] = __builtin_amdgcn_mfma_f32_16x16x32_bf16(xf[s][kk], wf, va[s][e], 0, 0, 0);
                }
            }
#pragma unroll
        for (int s = 0; s < 2; ++s)
#pragma unroll
            for (int e = 0; e < 2; ++e) {
                u16x4 pk, pv;
#pragma unroll
                for (int r = 0; r < 4; ++r) {
                    pk[r] = f2bf(__expf(ka[s][e][r]));
                    pv[r] = f2bf(va[s][e][r]);
                }
                int ch = e * 16 + lc;
                int pos = wv * 32 + s * 16 + lg * 4;
                int ba = (ch * 512 + pos * 2) ^ ((ch & 7) << 4);
                *(u16x4*)((char*)kt[bs] + ba) = pk;
                *(u16x4*)((char*)vt[bs] + ba) = pv;
            }
        __syncthreads();
        if (wv < 4) {
            f32x4 ca = {};
            float ks = 0.f;
#pragma unroll
            for (int k0 = 0; k0 < 256; k0 += 32) {
                int ar = di * 16 + lc, br = ei * 16 + lc;
                bf16x8 af = *(const bf16x8*)((const char*)kt[bs] + ((ar * 512 + (k0 + lg * 8) * 2) ^ ((ar & 7) << 4)));
                bf16x8 bf = *(const bf16x8*)((const char*)vt[bs] + ((br * 512 + (k0 + lg * 8) * 2) ^ ((br & 7) << 4)));
                if (ei == 0) {
#pragma unroll
                    for (int j = 0; j < 8; ++j) ks += bf2f((unsigned short)af[j]);
                }
                ca = __builtin_amdgcn_mfma_f32_16x16x32_bf16(af, bf, ca, 0, 0, 0);
            }
            float* cp = ctx_part + ((size_t)(b * 4 + h) * 128 + nblk) * 1024;
#pragma unroll
            for (int r = 0; r < 4; ++r)
                cp[(di * 16 + lg * 4 + r) * 32 + ei * 16 + lc] = ca[r];
            if (ei == 0) {
                ks += __shfl_xor(ks, 16);
                ks += __shfl_xor(ks, 32);
                if (lg == 0)
                    ksum_part[((size_t)(b * 4 + h) * 128 + nblk) * 32 + di * 16 + lc] = ks;
            }
        }
    }
}

// ==== kB: reduce ctx/ksum, Weff = wout·(ctx/ksum)  (256 blocks, 1 d each) ===
__global__ __launch_bounds__(256) void kB(const float* __restrict__ ctx_part,
        const float* __restrict__ ksum_part, const float* __restrict__ wout,
        unsigned short* __restrict__ weff) {
    __shared__ float c8[8][32];
    __shared__ float cred[32];
    __shared__ float ksr[2];
    __shared__ float ksv;
    const int blk = blockIdx.x;
    const int g = blk >> 5, ds = blk & 31;    // g = b*4+h; ds = d-channel
    const int bb = g >> 2, h = g & 3;
    const int t = threadIdx.x;
    const int e = t & 31, ii = t >> 5;        // ii 0..7
    float a = 0.f;
    const float* cp = ctx_part + (size_t)g * 128 * 1024 + ds * 32 + e;
#pragma unroll 4
    for (int i = ii * 16; i < ii * 16 + 16; ++i) a += cp[(size_t)i * 1024];
    c8[ii][e] = a;
    float ks = 0.f;
    if (t < 128) ks = ksum_part[((size_t)g * 128 + t) * 32 + ds];
#pragma unroll
    for (int off = 32; off > 0; off >>= 1) ks += __shfl_down(ks, off, 64);
    if (t < 128 && (t & 63) == 0) ksr[t >> 6] = ks;
    __syncthreads();
    if (t < 32) {
        float s = 0.f;
#pragma unroll
        for (int k = 0; k < 8; ++k) s += c8[k][t];
        cred[t] = s;
    }
    if (t == 0) ksv = ksr[0] + ksr[1];
    __syncthreads();
    if (t < 64) {
        const float* wrow = wout + t * HID + h * 32;
        float acc = 0.f;
#pragma unroll
        for (int e2 = 0; e2 < 32; ++e2) acc = fmaf(wrow[e2], cred[e2], acc);
        acc /= ksv;
        weff[((size_t)bb * 64 + t) * 128 + h * 32 + ds] = f2bf(acc);
    }
}

// ==== kC: y = Weff·q̂ from global frags; stats; y_t (pure PV, no LDS) =======
__global__ __launch_bounds__(256) void kC(const unsigned short* __restrict__ qs_frag,
        const unsigned short* __restrict__ weff, const float* __restrict__ bout,
        unsigned short* __restrict__ y_t, float* __restrict__ pstats) {
    __shared__ float red[8];
    const int t = threadIdx.x, wv = t >> 6, l = t & 63, lg = l >> 4, lc = l & 15;
    const int blk = blockIdx.x;
    const int b = blk >> 8, nblk = blk & 255;
    const int n0 = nblk * 128 + wv * 32;

    f32x4 acc[4][2] = {};   // [mt][s]
    const unsigned short* wb = weff + (size_t)b * 8192;
#pragma unroll
    for (int kk = 0; kk < 4; ++kk) {
        bf16x8 bq[2];
#pragma unroll
        for (int s = 0; s < 2; ++s) {
            int pos16 = nblk * 8 + wv * 2 + s;
            bq[s] = *(const bf16x8*)(qs_frag +
                ((size_t)(b * 2048 + pos16) * 4 + kk) * 512 + (size_t)l * 8);
        }
#pragma unroll
        for (int mt = 0; mt < 4; ++mt) {
            bf16x8 af = *(const bf16x8*)(wb + (size_t)(mt * 16 + lc) * 128 + kk * 32 + lg * 8);
#pragma unroll
            for (int s = 0; s < 2; ++s)
                acc[mt][s] = __builtin_amdgcn_mfma_f32_16x16x32_bf16(af, bq[s], acc[mt][s], 0, 0, 0);
        }
    }
    // bias + stats + y_t store ([n][o] bf16)
    float s1 = 0.f, s2 = 0.f;
#pragma unroll
    for (int mt = 0; mt < 4; ++mt) {
        float bo[4];
#pragma unroll
        for (int r = 0; r < 4; ++r) bo[r] = bout[mt * 16 + lg * 4 + r];
#pragma unroll
        for (int s = 0; s < 2; ++s) {
            u16x4 pk;
#pragma unroll
            for (int r = 0; r < 4; ++r) {
                float val = acc[mt][s][r] + bo[r];
                s1 += val;
                s2 = fmaf(val, val, s2);
                pk[r] = f2bf(val);
            }
            int n = n0 + s * 16 + lc;
            *(u16x4*)(y_t + ((size_t)b * N_SP + n) * 64 + mt * 16 + lg * 4) = pk;
        }
    }
#pragma unroll
    for (int off = 32; off > 0; off >>= 1) {
        s1 += __shfl_down(s1, off, 64);
        s2 += __shfl_down(s2, off, 64);
    }
    if (l == 0) { red[wv * 2] = s1; red[wv * 2 + 1] = s2; }
    __syncthreads();
    if (t == 0) {
        float S1 = red[0] + red[2] + red[4] + red[6];
        float S2 = red[1] + red[3] + red[5] + red[7];
        pstats[(b * 256 + nblk) * 2]     = S1;
        pstats[(b * 256 + nblk) * 2 + 1] = S2;
    }
}

// ==== kE: inline stats reduce (256 pairs), GN affine, y_t -> out ============
__global__ __launch_bounds__(256) void kE(const unsigned short* __restrict__ y_t,
        const float* __restrict__ pstats, const float* __restrict__ gnw,
        const float* __restrict__ gnb, float* __restrict__ out) {
    __shared__ float red[8];
    __shared__ float ms[2];
    __shared__ float w2s[64], b2s[64];
    const int t = threadIdx.x;
    const int blk = blockIdx.x;
    const int b = blk >> 9, nb = blk & 511;
    // reduce this batch's 256 stat pairs (redundant per block, L2-hot)
    float s1 = pstats[(b * 256 + t) * 2];
    float s2 = pstats[(b * 256 + t) * 2 + 1];
#pragma unroll
    for (int off = 32; off > 0; off >>= 1) {
        s1 += __shfl_down(s1, off, 64);
        s2 += __shfl_down(s2, off, 64);
    }
    if ((t & 63) == 0) { red[(t >> 6) * 2] = s1; red[(t >> 6) * 2 + 1] = s2; }
    __syncthreads();
    if (t == 0) {
        float S1 = red[0] + red[2] + red[4] + red[6];
        float S2 = red[1] + red[3] + red[5] + red[7];
        float mean = S1 / NGN;
        float var = S2 / NGN - mean * mean;
        ms[0] = mean; ms[1] = rsqrtf(var + GN_EPS_C);
    }
    __syncthreads();
    if (t < 64) {
        float w2 = gnw[t] * ms[1];
        w2s[t] = w2;
        b2s[t] = gnb[t] - ms[0] * w2;
    }
    __syncthreads();
    // n = nb*64 + (t&63): wave-contiguous out-writes (256 B per o-plane)
    const int n = nb * 64 + (t & 63), o0 = (t >> 6) * 16;
    const unsigned short* yp = y_t + ((size_t)b * N_SP + n) * 64 + o0;
    u16x8 v0 = *(const u16x8*)yp;
    u16x8 v1 = *(const u16x8*)(yp + 8);
    float* ob = out + (size_t)b * C_IN * N_SP + n;
#pragma unroll
    for (int j = 0; j < 8; ++j)
        ob[(size_t)(o0 + j) * N_SP] = fmaf(bf2f((unsigned short)v0[j]), w2s[o0 + j], b2s[o0 + j]);
#pragma unroll
    for (int j = 0; j < 8; ++j)
        ob[(size_t)(o0 + 8 + j) * N_SP] = fmaf(bf2f((unsigned short)v1[j]), w2s[o0 + 8 + j], b2s[o0 + 8 + j]);
}

extern "C" void kernel_launch(void* const* d_in, const int* in_sizes, int n_in,
                              void* d_out, int out_size, void* d_ws, size_t ws_size,
                              hipStream_t stream) {
    const float* x    = (const float*)d_in[0];
    const float* wqkv = (const float*)d_in[1];
    const float* wout = (const float*)d_in[2];
    const float* bout = (const float*)d_in[3];
    const float* gnw  = (const float*)d_in[4];
    const float* gnb  = (const float*)d_in[5];
    float* out = (float*)d_out;

    char* ws = (char*)d_ws;
    size_t off = 0;
    unsigned short* qs_frag = (unsigned short*)(ws + off); off += (size_t)NB * 2048 * 4 * 512 * 2;  // 16.8 MB
    float* ctx_part  = (float*)(ws + off); off += (size_t)8 * 128 * 1024 * 4;   // 4 MB
    float* ksum_part = (float*)(ws + off); off += (size_t)8 * 128 * 32 * 4;     // 128 KB
    unsigned short* weff = (unsigned short*)(ws + off); off += 2 * 8192 * 2;    // 32 KB
    unsigned short* y_t  = (unsigned short*)(ws + off); off += (size_t)NB * N_SP * 64 * 2;  // 8.4 MB
    float* pstats = (float*)(ws + off); off += NB * 256 * 2 * 4;

    kA<<<dim3(256), dim3(512), 0, stream>>>(x, wqkv, qs_frag, ctx_part, ksum_part);
    kB<<<dim3(256), dim3(256), 0, stream>>>(ctx_part, ksum_part, wout, weff);
    kC<<<dim3(512), dim3(256), 0, stream>>>(qs_frag, weff, bout, y_t, pstats);
    kE<<<dim3(1024), dim3(256), 0, stream>>>(y_t, pstats, gnw, gnb, out);
}